// Round 14
// baseline (220.788 us; speedup 1.0000x reference)
//
#include <hip/hip_runtime.h>
#include <hip/hip_bf16.h>

typedef unsigned short USHORT;
typedef long long LL;
typedef short s8v __attribute__((ext_vector_type(8)));
typedef float f32x4 __attribute__((ext_vector_type(4)));

// B=2, L=256, H=512, NH=8, DH=64, MAXLEN=256, PE_ROWS=513
// Dtypes runtime-detected: floats f32-or-bf16 (canonicalized bf16), ints i32-or-i64.
// R14: 5 dispatches. vwr+WrT folded into prep (vwr from raw Wr/v); mid merged into g2
// (bid<768 gemm tiles, 768-895 T-table, 896-959 cbv/uk).

__device__ __forceinline__ float bf2f(USHORT u) {
  union { unsigned int i; float f; } v; v.i = ((unsigned int)u) << 16; return v.f;
}
__device__ __forceinline__ USHORT f2bf(float f) {
  unsigned int x = __float_as_uint(f);
  return (USHORT)((x + 0x7fffu + ((x >> 16) & 1u)) >> 16);
}

// ---------------- prep: detect + canonicalize + WrT + vwr + ints + flags ----------------
struct PrepArgs {
  const void* fsrc[18]; USHORT* fdst[18]; int fn[18];
  const void* wr_src; USHORT* wrT; USHORT* vwr;
  const void* isrc[4]; int* idst[4];
};

__global__ __launch_bounds__(256) void prep_k(PrepArgs a, const void* qraw, int* flags) {
  __shared__ int s_w;
  const int t = threadIdx.x;
  if (t == 0) s_w = 0;
  __syncthreads();
  const USHORT* qb = (const USHORT*)qraw;
  int wild = 0;
  for (int c = t; c < 512; c += 256) {
    float x = bf2f(qb[c]);
    if (!(fabsf(x) <= 1024.0f)) wild = 1;  // catches NaN too
  }
  if (wild) atomicAdd(&s_w, 1);
  __syncthreads();
  const int f = (s_w == 0) ? 1 : 0;  // 1 iff float inputs are bf16

  const int y = blockIdx.y;
  if (y < 18) {
    if (y == 12) return;  // Wr consumed only via WrT/vwr
    const int n = a.fn[y];
    const USHORT* sb = (const USHORT*)a.fsrc[y];
    const float* sf = (const float*)a.fsrc[y];
    USHORT* d = a.fdst[y];
    for (int idx = blockIdx.x * 256 + t; idx < n; idx += gridDim.x * 256)
      d[idx] = f ? sb[idx] : f2bf(sf[idx]);
  } else if (y == 18) {
    const USHORT* sb = (const USHORT*)a.wr_src;
    const float* sf = (const float*)a.wr_src;
    for (int idx = blockIdx.x * 256 + t; idx < 262144; idx += gridDim.x * 256) {
      const int e = idx >> 9, dd = idx & 511;
      const int s = dd * 512 + e;
      a.wrT[idx] = f ? sb[s] : f2bf(sf[s]);  // WrT[e][d] = Wr[d][e]
    }
  } else if (y == 19) {
    // vwr[h*512+e] = sum_d bf(v[h,d]) * bf(Wr[h*64+d][e])  (from RAW inputs)
    const int o = blockIdx.x * 256 + t;
    if (o < 4096) {
      const int h = o >> 9, e = o & 511;
      const USHORT* wb = (const USHORT*)a.wr_src;
      const float* wf = (const float*)a.wr_src;
      const USHORT* vb = (const USHORT*)a.fsrc[17];
      const float* vf = (const float*)a.fsrc[17];
      float s = 0.f;
#pragma unroll 4
      for (int d = 0; d < 64; d += 4) {
        float acc4 = 0.f;
#pragma unroll
        for (int dd = 0; dd < 4; dd++) {
          const int hd = h * 64 + d + dd;
          const float vv = bf2f(f ? vb[hd] : f2bf(vf[hd]));
          const float wv = bf2f(f ? wb[(long)hd * 512 + e] : f2bf(wf[(long)hd * 512 + e]));
          acc4 += vv * wv;
        }
        s += acc4;
      }
      a.vwr[o] = f2bf(s);
    }
  } else if (blockIdx.x == 0) {
    if (t == 0) flags[0] = f;
    const int fi = (((const int*)a.isrc[0])[1] == 0) ? 1 : 0;  // seq_len[0] in [100,200)
    if (t < 2) {
      a.idst[0][t] = fi ? (int)((const LL*)a.isrc[0])[t] : ((const int*)a.isrc[0])[t];
      a.idst[1][t] = fi ? (int)((const LL*)a.isrc[1])[t] : ((const int*)a.isrc[1])[t];
    }
    for (int c = t; c < 512; c += 256) {
      a.idst[2][c] = fi ? (int)((const LL*)a.isrc[2])[c] : ((const int*)a.isrc[2])[c];
      a.idst[3][c] = fi ? (int)((const LL*)a.isrc[3])[c] : ((const int*)a.isrc[3])[c];
    }
  }
}

// ---------------- shared MFMA 64x64 tile ----------------
struct GDesc {
  const USHORT* A; const USHORT* W; const USHORT* bias;
  void* out;
  int M, N, K, lda, ldw, koff, ldo, mode, trans, pad;  // mode: 0 f32, 1 bf16, 2 per-flag
};
struct GArgs { GDesc d[32]; };

__device__ __forceinline__ void gemm_tile(const GDesc& de, int row0, int col0, int t,
                                          const int* __restrict__ flags) {
  if (row0 >= de.M || col0 >= de.N) return;
  const int wave = t >> 6, lane = t & 63;
  const int mrow = row0 + wave * 16 + (lane & 15);
  const int kq = (lane >> 4) * 8;
  const bool mok = (mrow < de.M);
  const USHORT* ar = de.A + (long)(mok ? mrow : row0) * de.lda + kq;
  const int nc = col0 + (lane & 15);
  const USHORT* w0p = de.W + (long)(nc +  0) * de.ldw + de.koff + kq;
  const USHORT* w1p = de.W + (long)(nc + 16) * de.ldw + de.koff + kq;
  const USHORT* w2p = de.W + (long)(nc + 32) * de.ldw + de.koff + kq;
  const USHORT* w3p = de.W + (long)(nc + 48) * de.ldw + de.koff + kq;

  f32x4 acc[4] = {};
#pragma unroll 4
  for (int k0 = 0; k0 < de.K; k0 += 32) {
    s8v a = *(const s8v*)(ar + k0);
    s8v wv0 = *(const s8v*)(w0p + k0);
    s8v wv1 = *(const s8v*)(w1p + k0);
    s8v wv2 = *(const s8v*)(w2p + k0);
    s8v wv3 = *(const s8v*)(w3p + k0);
    acc[0] = __builtin_amdgcn_mfma_f32_16x16x32_bf16(a, wv0, acc[0], 0, 0, 0);
    acc[1] = __builtin_amdgcn_mfma_f32_16x16x32_bf16(a, wv1, acc[1], 0, 0, 0);
    acc[2] = __builtin_amdgcn_mfma_f32_16x16x32_bf16(a, wv2, acc[2], 0, 0, 0);
    acc[3] = __builtin_amdgcn_mfma_f32_16x16x32_bf16(a, wv3, acc[3], 0, 0, 0);
  }

  const int obf = (de.mode == 2) ? flags[0] : (de.mode == 1);
  const int mbase = row0 + wave * 16 + (lane >> 4) * 4;
#pragma unroll
  for (int nt = 0; nt < 4; nt++) {
    const int n = col0 + nt * 16 + (lane & 15);
    const float bias = de.bias ? bf2f(de.bias[n]) : 0.f;
#pragma unroll
    for (int r = 0; r < 4; r++) {
      const int m = mbase + r;
      if (m >= de.M) continue;
      const float vo = acc[nt][r] + bias;
      const long off = de.trans ? ((long)n * de.ldo + m) : ((long)m * de.ldo + n);
      if (obf) ((USHORT*)de.out)[off] = f2bf(vo);
      else     ((float*)de.out)[off] = vo;
    }
  }
}

__global__ __launch_bounds__(256) void gemm2_k(GArgs ga, const int* __restrict__ flags) {
  gemm_tile(ga.d[blockIdx.z], blockIdx.y * 64, blockIdx.x * 64, threadIdx.x, flags);
}

// ---------------- g2mid: wproj + S_AC tiles, T-table, cbv/uk in one kernel ----------------
__global__ __launch_bounds__(256) void g2mid_k(
    GArgs ga, const USHORT* __restrict__ Ptab,
    const USHORT* __restrict__ q_n, const USHORT* __restrict__ k_n,
    const USHORT* __restrict__ u_bf, const USHORT* __restrict__ v_bf,
    const USHORT* __restrict__ br_bf,
    USHORT* __restrict__ T, float* __restrict__ cbv, float* __restrict__ uk,
    const int* __restrict__ flags)
{
  const int bid = blockIdx.x, t = threadIdx.x;
  if (bid < 768) {
    int z, uy, ux;
    if (bid < 512) { z = bid >> 5; const int tile = bid & 31; ux = tile >> 2; uy = tile & 3; }
    else { const int b2 = bid - 512; z = 16 + (b2 >> 4); const int tile = b2 & 15; ux = tile >> 2; uy = tile & 3; }
    gemm_tile(ga.d[z], uy * 64, ux * 64, t, flags);
  } else if (bid < 896) {
    const long TS = 513l * 512;
    for (int r = bid - 768; r < 12825; r += 128) {
      const int S0 = r / 25, rem = r % 25, di = rem / 5, dj = rem % 5;
      const USHORT* p1 = Ptab + (long)S0 * 512;
      const USHORT* p2 = Ptab + TS + (long)max(S0 - dj, 0) * 512;
      const USHORT* p3 = Ptab + 2 * TS + (long)min(S0 + di, 512) * 512;
      const USHORT* p4 = Ptab + 3 * TS + (long)min(max(S0 + di - dj, 0), 512) * 512;
      USHORT* to = T + (long)r * 512;
      const int e = t * 2;
      ushort2 x1 = *(const ushort2*)(p1 + e);
      ushort2 x2 = *(const ushort2*)(p2 + e);
      ushort2 x3 = *(const ushort2*)(p3 + e);
      ushort2 x4 = *(const ushort2*)(p4 + e);
      ushort2 o;
      o.x = f2bf(fmaxf(bf2f(x1.x) + bf2f(x2.x) + bf2f(x3.x) + bf2f(x4.x), 0.f));
      o.y = f2bf(fmaxf(bf2f(x1.y) + bf2f(x2.y) + bf2f(x3.y) + bf2f(x4.y), 0.f));
      *(ushort2*)(to + e) = o;
    }
  } else {
    for (int idx = (bid - 896) * 256 + t; idx < 262144; idx += 64 * 256) {
      const int hd = idx & 511;
      float s = (bf2f(q_n[idx]) + bf2f(v_bf[hd])) * bf2f(br_bf[hd]);
      float s2 = bf2f(k_n[idx]) * bf2f(u_bf[hd]);
#pragma unroll
      for (int off = 32; off > 0; off >>= 1) { s += __shfl_xor(s, off); s2 += __shfl_xor(s2, off); }
      if ((t & 63) == 0) { cbv[idx >> 6] = s; uk[idx >> 6] = s2; }
    }
  }
}

// ---------------- fused score + softmax + attn@V: one block per (b,i), 16 waves -------
__global__ __launch_bounds__(1024) void score6_k(
    const USHORT* __restrict__ T,
    const float* __restrict__ cbv, const float* __restrict__ uk,
    const USHORT* __restrict__ wbuf, const float* __restrict__ S_AC,
    const USHORT* __restrict__ v_t,
    const int* __restrict__ seq_len, const int* __restrict__ lex_num,
    const int* __restrict__ pos_s, const int* __restrict__ pos_e,
    USHORT* __restrict__ out_pre)
{
  __shared__ float att[8 * 256];
  __shared__ float red[4][4];
  const int i = blockIdx.x, b = blockIdx.y, t = threadIdx.x;
  const int wave = t >> 6, lane = t & 63;
  int tl = seq_len[b] + lex_num[b];
  tl = min(max(tl, 1), 256);

  const int j0 = wave * 16;
  if (j0 < tl) {
    const int n = lane & 15, q = lane >> 4;
    const int psi = pos_s[b * 256 + i], pei = pos_e[b * 256 + i];
    const int j = j0 + n;
    const int psj = pos_s[b * 256 + j], pej = pos_e[b * 256 + j];
    const int S0 = min(max(psi - psj + 256, 0), 512);
    const int di = min(max(pei - psi, 0), 4);
    const int dj = min(max(pej - psj, 0), 4);
    const USHORT* tp = T + ((long)(S0 * 25 + di * 5 + dj)) * 512 + q * 8;
    const USHORT* wr = wbuf + ((long)((b * 8 + (n & 7)) * 256 + i)) * 512 + q * 8;
    f32x4 acc = {0.f, 0.f, 0.f, 0.f};
#pragma unroll
    for (int kk = 0; kk < 16; kk++) {
      s8v av = *(const s8v*)(tp + kk * 32);
      s8v wv = *(const s8v*)(wr + kk * 32);  // n>=8 duplicates h=n-8; D cols discarded
      acc = __builtin_amdgcn_mfma_f32_16x16x32_bf16(av, wv, acc, 0, 0, 0);
    }
    if (n < 8) {  // D: col h = lane&15, row j_local = q*4+r
      const long base = (long)(b * 8 + n) * 256 + i;
      const float cb = cbv[(long)(b * 256 + i) * 8 + n];
      const float4 sac = *(const float4*)(S_AC + base * 256 + j0 + q * 4);
      const float* sacp = (const float*)&sac;
#pragma unroll
      for (int r = 0; r < 4; r++) {
        const int jr = j0 + q * 4 + r;
        att[n * 256 + jr] = (acc[r] + sacp[r] + cb + uk[(long)(b * 256 + jr) * 8 + n]) * 0.125f;
      }
    }
  }
  __syncthreads();

  const int hg = t >> 8, tj = t & 255, wig = wave & 3;
#pragma unroll
  for (int hh = 0; hh < 2; hh++) {
    const int h = hg + 4 * hh;
    const float val = (tj < tl) ? att[h * 256 + tj] : -3.0e38f;
    float m = val;
#pragma unroll
    for (int off = 32; off > 0; off >>= 1) m = fmaxf(m, __shfl_xor(m, off));
    if (lane == 0) red[hg][wig] = m;
    __syncthreads();
    m = fmaxf(fmaxf(red[hg][0], red[hg][1]), fmaxf(red[hg][2], red[hg][3]));
    const float pv = (tj < tl) ? __expf(val - m) : 0.f;
    float s = pv;
#pragma unroll
    for (int off = 32; off > 0; off >>= 1) s += __shfl_xor(s, off);
    __syncthreads();
    if (lane == 0) red[hg][wig] = s;
    __syncthreads();
    s = red[hg][0] + red[hg][1] + red[hg][2] + red[hg][3];
    if (!(s > 1e-30f)) s = 1.f;
    att[h * 256 + tj] = pv / s;  // all 256 j written: masked tail exact 0
    __syncthreads();
  }

  if (t < 512) {
    const int h = t >> 6, d = t & 63;
    const USHORT* vrow = v_t + (long)(h * 64 + d) * 512 + b * 256;
    const float* arow = &att[h * 256];
    float acc = 0.f;
    const int tl4 = (tl + 3) & ~3;
    for (int jj = 0; jj < tl4; jj += 4) {
      ushort4 vv = *(const ushort4*)(vrow + jj);
      acc += arow[jj + 0] * bf2f(vv.x) + arow[jj + 1] * bf2f(vv.y) +
             arow[jj + 2] * bf2f(vv.z) + arow[jj + 3] * bf2f(vv.w);
    }
    out_pre[(long)(b * 256 + i) * 512 + h * 64 + d] = f2bf(acc);
  }
}

extern "C" void kernel_launch(void* const* d_in, const int* in_sizes, int n_in,
                              void* d_out, int out_size, void* d_ws, size_t ws_size,
                              hipStream_t stream) {
  (void)in_sizes; (void)n_in; (void)out_size; (void)ws_size;

  char* w = (char*)d_ws;
  auto take = [&](size_t n) { char* r = w; w += (n + 255) & ~(size_t)255; return r; };

  int* flags   = (int*)take(16);
  int* c_seq   = (int*)take(16);
  int* c_lex   = (int*)take(16);
  int* c_pos_s = (int*)take(2048);
  int* c_pos_e = (int*)take(2048);
  const int ns[18] = {262144,262144,262144,262656,1048576,512,262144,512,262144,512,
                      262144,512,262144,512,262144,512,512,512};
  USHORT* canon[18];
  for (int i = 0; i < 18; i++) canon[i] = (USHORT*)take(i == 12 ? 1024 : (size_t)ns[i] * 2);
  USHORT* WrT     = (USHORT*)take((size_t)262144 * 2);
  USHORT* q_n     = (USHORT*)take((size_t)262144 * 2);
  USHORT* k_n     = (USHORT*)take((size_t)262144 * 2);
  USHORT* v_t     = (USHORT*)take((size_t)262144 * 2);
  USHORT* wbuf    = (USHORT*)take((size_t)2097152 * 2);
  USHORT* Ptab    = (USHORT*)take((size_t)1050624 * 2);
  USHORT* T       = (USHORT*)take((size_t)12825 * 512 * 2);
  USHORT* vwr     = (USHORT*)take((size_t)4096 * 2);
  USHORT* out_pre = (USHORT*)take((size_t)262144 * 2);
  float* S   = (float*)take((size_t)1048576 * 4);   // S_AC only
  float* cbv = (float*)take((size_t)4096 * 4);
  float* uk  = (float*)take((size_t)4096 * 4);

  // 1) prep (canon + WrT + vwr + ints + flags)
  PrepArgs pa;
  for (int i = 0; i < 18; i++) { pa.fsrc[i] = d_in[i]; pa.fdst[i] = canon[i]; pa.fn[i] = ns[i]; }
  pa.wr_src = d_in[12]; pa.wrT = WrT; pa.vwr = vwr;
  for (int i = 0; i < 4; i++) pa.isrc[i] = d_in[18 + i];
  pa.idst[0] = c_seq; pa.idst[1] = c_lex; pa.idst[2] = c_pos_s; pa.idst[3] = c_pos_e;
  prep_k<<<dim3(64, 21), 256, 0, stream>>>(pa, d_in[1], flags);

  // 2) g1: P tables (bf16, +bf in tbl0) + q/k (bf16) + v (bf16, transposed)
  GArgs gA = {};
  for (int z = 0; z < 4; z++)
    gA.d[z] = {canon[3], canon[4], (z == 0) ? canon[5] : nullptr, Ptab + (long)z * 513 * 512,
               513, 512, 512, 512, 2048, z * 512, 512, 1, 0, 0};
  gA.d[4] = {canon[1], canon[8],  canon[9],  q_n, 512, 512, 512, 512, 512, 0, 512, 1, 0, 0};
  gA.d[5] = {canon[0], canon[6],  canon[7],  k_n, 512, 512, 512, 512, 512, 0, 512, 1, 0, 0};
  gA.d[6] = {canon[2], canon[10], canon[11], v_t, 512, 512, 512, 512, 512, 0, 512, 1, 1, 0};
  gemm2_k<<<dim3(8, 9, 7), 256, 0, stream>>>(gA, flags);

  // 3) g2mid: wproj + S_AC tiles + T table + cbv/uk
  GArgs gB = {};
  for (int z = 0; z < 16; z++) {
    const int b = z >> 3, h = z & 7;
    gB.d[z] = {q_n + b * 131072 + h * 64, WrT, vwr + h * 512, wbuf + (long)z * 131072,
               256, 512, 64, 512, 512, h * 64, 512, 1, 0, 0};
  }
  for (int z = 0; z < 16; z++) {
    const int b = z >> 3, h = z & 7;
    gB.d[16 + z] = {q_n + b * 131072 + h * 64, k_n + b * 131072 + h * 64, nullptr,
                    S + (long)z * 65536, 256, 256, 64, 512, 512, 0, 256, 0, 0, 0};
  }
  g2mid_k<<<960, 256, 0, stream>>>(gB, Ptab, q_n, k_n, canon[16], canon[17], canon[13],
                                   T, cbv, uk, flags);

  // 4) fused score + softmax + attn@V -> out_pre (bf16)
  score6_k<<<dim3(256, 2), 1024, 0, stream>>>(
      T, cbv, uk, wbuf, S, v_t, c_seq, c_lex, c_pos_s, c_pos_e, out_pre);

  // 5) final: out = out_pre @ Wo.T + bo -> d_out (dtype per flag)
  GArgs gC = {};
  gC.d[0] = {out_pre, canon[14], canon[15], d_out, 512, 512, 512, 512, 512, 0, 512, 2, 0, 0};
  gemm2_k<<<dim3(8, 8, 1), 256, 0, stream>>>(gC, flags);
}

// Round 15
// 216.653 us; speedup vs baseline: 1.0191x; 1.0191x over previous
//
#include <hip/hip_runtime.h>
#include <hip/hip_bf16.h>

typedef unsigned short USHORT;
typedef long long LL;
typedef short s8v __attribute__((ext_vector_type(8)));
typedef float f32x4 __attribute__((ext_vector_type(4)));

// B=2, L=256, H=512, NH=8, DH=64, MAXLEN=256, PE_ROWS=513
// Dtypes runtime-detected: floats f32-or-bf16 (canonicalized bf16), ints i32-or-i64.
// R15 = R13 revert (best measured: 216.9 us). R14's 5-dispatch merge regressed
// (uncoalesced raw-Wr vwr reads + lumpy g2mid blocks) -> 6 clean dispatches win.

__device__ __forceinline__ float bf2f(USHORT u) {
  union { unsigned int i; float f; } v; v.i = ((unsigned int)u) << 16; return v.f;
}
__device__ __forceinline__ USHORT f2bf(float f) {
  unsigned int x = __float_as_uint(f);
  return (USHORT)((x + 0x7fffu + ((x >> 16) & 1u)) >> 16);
}

// ---------------- prep: dtype-detect + canonicalize + WrT + ints + flags ----------------
struct PrepArgs {
  const void* fsrc[18]; USHORT* fdst[18]; int fn[18];
  const void* wr_src; USHORT* wrT;
  const void* isrc[4]; int* idst[4];
};

__global__ __launch_bounds__(256) void prep_k(PrepArgs a, const void* qraw, int* flags) {
  __shared__ int s_w;
  const int t = threadIdx.x;
  if (t == 0) s_w = 0;
  __syncthreads();
  const USHORT* qb = (const USHORT*)qraw;
  int wild = 0;
  for (int c = t; c < 512; c += 256) {
    float x = bf2f(qb[c]);
    if (!(fabsf(x) <= 1024.0f)) wild = 1;  // catches NaN too
  }
  if (wild) atomicAdd(&s_w, 1);
  __syncthreads();
  const int f = (s_w == 0) ? 1 : 0;  // 1 iff float inputs are bf16

  const int y = blockIdx.y;
  if (y < 18) {
    const int n = a.fn[y];
    const USHORT* sb = (const USHORT*)a.fsrc[y];
    const float* sf = (const float*)a.fsrc[y];
    USHORT* d = a.fdst[y];
    for (int idx = blockIdx.x * 256 + t; idx < n; idx += gridDim.x * 256)
      d[idx] = f ? sb[idx] : f2bf(sf[idx]);
  } else if (y == 18) {
    const USHORT* sb = (const USHORT*)a.wr_src;
    const float* sf = (const float*)a.wr_src;
    for (int idx = blockIdx.x * 256 + t; idx < 262144; idx += gridDim.x * 256) {
      const int e = idx >> 9, dd = idx & 511;
      const int s = dd * 512 + e;
      a.wrT[idx] = f ? sb[s] : f2bf(sf[s]);  // WrT[e][d] = Wr[d][e]
    }
  } else if (blockIdx.x == 0) {
    if (t == 0) flags[0] = f;
    const int fi = (((const int*)a.isrc[0])[1] == 0) ? 1 : 0;  // seq_len[0] in [100,200)
    if (t < 2) {
      a.idst[0][t] = fi ? (int)((const LL*)a.isrc[0])[t] : ((const int*)a.isrc[0])[t];
      a.idst[1][t] = fi ? (int)((const LL*)a.isrc[1])[t] : ((const int*)a.isrc[1])[t];
    }
    for (int c = t; c < 512; c += 256) {
      a.idst[2][c] = fi ? (int)((const LL*)a.isrc[2])[c] : ((const int*)a.isrc[2])[c];
      a.idst[3][c] = fi ? (int)((const LL*)a.isrc[3])[c] : ((const int*)a.isrc[3])[c];
    }
  }
}

// ---------------- generic multi-desc MFMA GEMM (R7-proven) ----------------
struct GDesc {
  const USHORT* A; const USHORT* W; const USHORT* bias;
  void* out;
  int M, N, K, lda, ldw, koff, ldo, mode, trans, pad;  // mode: 0 f32, 1 bf16, 2 per-flag
};
struct GArgs { GDesc d[32]; };

__global__ __launch_bounds__(256) void gemm2_k(GArgs ga, const int* __restrict__ flags) {
  const GDesc de = ga.d[blockIdx.z];
  const int row0 = blockIdx.y * 64, col0 = blockIdx.x * 64;
  if (row0 >= de.M || col0 >= de.N) return;
  const int wave = threadIdx.x >> 6, lane = threadIdx.x & 63;
  const int mrow = row0 + wave * 16 + (lane & 15);
  const int kq = (lane >> 4) * 8;
  const bool mok = (mrow < de.M);
  const USHORT* ar = de.A + (long)(mok ? mrow : row0) * de.lda + kq;
  const int nc = col0 + (lane & 15);
  const USHORT* w0p = de.W + (long)(nc +  0) * de.ldw + de.koff + kq;
  const USHORT* w1p = de.W + (long)(nc + 16) * de.ldw + de.koff + kq;
  const USHORT* w2p = de.W + (long)(nc + 32) * de.ldw + de.koff + kq;
  const USHORT* w3p = de.W + (long)(nc + 48) * de.ldw + de.koff + kq;

  f32x4 acc[4] = {};
#pragma unroll 4
  for (int k0 = 0; k0 < de.K; k0 += 32) {
    s8v a = *(const s8v*)(ar + k0);
    s8v wv0 = *(const s8v*)(w0p + k0);
    s8v wv1 = *(const s8v*)(w1p + k0);
    s8v wv2 = *(const s8v*)(w2p + k0);
    s8v wv3 = *(const s8v*)(w3p + k0);
    acc[0] = __builtin_amdgcn_mfma_f32_16x16x32_bf16(a, wv0, acc[0], 0, 0, 0);
    acc[1] = __builtin_amdgcn_mfma_f32_16x16x32_bf16(a, wv1, acc[1], 0, 0, 0);
    acc[2] = __builtin_amdgcn_mfma_f32_16x16x32_bf16(a, wv2, acc[2], 0, 0, 0);
    acc[3] = __builtin_amdgcn_mfma_f32_16x16x32_bf16(a, wv3, acc[3], 0, 0, 0);
  }

  const int obf = (de.mode == 2) ? flags[0] : (de.mode == 1);
  const int mbase = row0 + wave * 16 + (lane >> 4) * 4;
#pragma unroll
  for (int nt = 0; nt < 4; nt++) {
    const int n = col0 + nt * 16 + (lane & 15);
    const float bias = de.bias ? bf2f(de.bias[n]) : 0.f;
#pragma unroll
    for (int r = 0; r < 4; r++) {
      const int m = mbase + r;
      if (m >= de.M) continue;
      const float vo = acc[nt][r] + bias;
      const long off = de.trans ? ((long)n * de.ldo + m) : ((long)m * de.ldo + n);
      if (obf) ((USHORT*)de.out)[off] = f2bf(vo);
      else     ((float*)de.out)[off] = vo;
    }
  }
}

// ---------------- mid: full relu T-table + cbv + uk + vwr ----------------
__global__ __launch_bounds__(256) void mid_k(
    const USHORT* __restrict__ Ptab, const USHORT* __restrict__ q_n,
    const USHORT* __restrict__ k_n, const USHORT* __restrict__ WrT,
    const USHORT* __restrict__ u_bf, const USHORT* __restrict__ v_bf,
    const USHORT* __restrict__ br_bf,
    USHORT* __restrict__ T,
    float* __restrict__ cbv, float* __restrict__ uk, USHORT* __restrict__ vwr)
{
  const int bid = blockIdx.x, t = threadIdx.x, gsz = gridDim.x;
  const long TS = 513l * 512;
  for (int r = bid; r < 12825; r += gsz) {
    const int S0 = r / 25, rem = r % 25, di = rem / 5, dj = rem % 5;
    const USHORT* p1 = Ptab + (long)S0 * 512;
    const USHORT* p2 = Ptab + TS + (long)max(S0 - dj, 0) * 512;
    const USHORT* p3 = Ptab + 2 * TS + (long)min(S0 + di, 512) * 512;
    const USHORT* p4 = Ptab + 3 * TS + (long)min(max(S0 + di - dj, 0), 512) * 512;
    USHORT* to = T + (long)r * 512;
    const int e = t * 2;
    ushort2 x1 = *(const ushort2*)(p1 + e);
    ushort2 x2 = *(const ushort2*)(p2 + e);
    ushort2 x3 = *(const ushort2*)(p3 + e);
    ushort2 x4 = *(const ushort2*)(p4 + e);
    ushort2 o;
    o.x = f2bf(fmaxf(bf2f(x1.x) + bf2f(x2.x) + bf2f(x3.x) + bf2f(x4.x), 0.f));
    o.y = f2bf(fmaxf(bf2f(x1.y) + bf2f(x2.y) + bf2f(x3.y) + bf2f(x4.y), 0.f));
    *(ushort2*)(to + e) = o;
  }
  for (int idx = bid * 256 + t; idx < 262144; idx += gsz * 256) {
    const int hd = idx & 511;
    float s = (bf2f(q_n[idx]) + bf2f(v_bf[hd])) * bf2f(br_bf[hd]);
    float s2 = bf2f(k_n[idx]) * bf2f(u_bf[hd]);
#pragma unroll
    for (int off = 32; off > 0; off >>= 1) { s += __shfl_xor(s, off); s2 += __shfl_xor(s2, off); }
    if ((t & 63) == 0) { cbv[idx >> 6] = s; uk[idx >> 6] = s2; }
  }
  for (int o = bid * 256 + t; o < 4096; o += gsz * 256) {
    const int h = o >> 9, e = o & 511;
    float s = 0.f;
    const USHORT* wrow = WrT + (long)e * 512 + h * 64;
    const USHORT* vrow = v_bf + h * 64;
#pragma unroll
    for (int d = 0; d < 64; d += 4) {
      ushort4 wv = *(const ushort4*)(wrow + d);
      ushort4 vv = *(const ushort4*)(vrow + d);
      s += bf2f(vv.x) * bf2f(wv.x) + bf2f(vv.y) * bf2f(wv.y) +
           bf2f(vv.z) * bf2f(wv.z) + bf2f(vv.w) * bf2f(wv.w);
    }
    vwr[o] = f2bf(s);  // vwr[h*512+e]
  }
}

// ---------------- fused score + softmax + attn@V: one block per (b,i), 16 waves -------
__global__ __launch_bounds__(1024) void score6_k(
    const USHORT* __restrict__ T,
    const float* __restrict__ cbv, const float* __restrict__ uk,
    const USHORT* __restrict__ wbuf, const float* __restrict__ S_AC,
    const USHORT* __restrict__ v_t,
    const int* __restrict__ seq_len, const int* __restrict__ lex_num,
    const int* __restrict__ pos_s, const int* __restrict__ pos_e,
    USHORT* __restrict__ out_pre)
{
  __shared__ float att[8 * 256];
  __shared__ float red[4][4];
  const int i = blockIdx.x, b = blockIdx.y, t = threadIdx.x;
  const int wave = t >> 6, lane = t & 63;
  int tl = seq_len[b] + lex_num[b];
  tl = min(max(tl, 1), 256);

  const int j0 = wave * 16;
  if (j0 < tl) {
    const int n = lane & 15, q = lane >> 4;
    const int psi = pos_s[b * 256 + i], pei = pos_e[b * 256 + i];
    const int j = j0 + n;
    const int psj = pos_s[b * 256 + j], pej = pos_e[b * 256 + j];
    const int S0 = min(max(psi - psj + 256, 0), 512);
    const int di = min(max(pei - psi, 0), 4);
    const int dj = min(max(pej - psj, 0), 4);
    const USHORT* tp = T + ((long)(S0 * 25 + di * 5 + dj)) * 512 + q * 8;
    const USHORT* wr = wbuf + ((long)((b * 8 + (n & 7)) * 256 + i)) * 512 + q * 8;
    f32x4 acc = {0.f, 0.f, 0.f, 0.f};
#pragma unroll
    for (int kk = 0; kk < 16; kk++) {
      s8v av = *(const s8v*)(tp + kk * 32);
      s8v wv = *(const s8v*)(wr + kk * 32);  // n>=8 duplicates h=n-8; D cols discarded
      acc = __builtin_amdgcn_mfma_f32_16x16x32_bf16(av, wv, acc, 0, 0, 0);
    }
    if (n < 8) {  // D: col h = lane&15, row j_local = q*4+r
      const long base = (long)(b * 8 + n) * 256 + i;
      const float cb = cbv[(long)(b * 256 + i) * 8 + n];
      const float4 sac = *(const float4*)(S_AC + base * 256 + j0 + q * 4);
      const float* sacp = (const float*)&sac;
#pragma unroll
      for (int r = 0; r < 4; r++) {
        const int jr = j0 + q * 4 + r;
        att[n * 256 + jr] = (acc[r] + sacp[r] + cb + uk[(long)(b * 256 + jr) * 8 + n]) * 0.125f;
      }
    }
  }
  __syncthreads();

  // softmax: subgroup hg (256 thr) handles heads hg and hg+4
  const int hg = t >> 8, tj = t & 255, wig = wave & 3;
#pragma unroll
  for (int hh = 0; hh < 2; hh++) {
    const int h = hg + 4 * hh;
    const float val = (tj < tl) ? att[h * 256 + tj] : -3.0e38f;
    float m = val;
#pragma unroll
    for (int off = 32; off > 0; off >>= 1) m = fmaxf(m, __shfl_xor(m, off));
    if (lane == 0) red[hg][wig] = m;
    __syncthreads();
    m = fmaxf(fmaxf(red[hg][0], red[hg][1]), fmaxf(red[hg][2], red[hg][3]));
    const float pv = (tj < tl) ? __expf(val - m) : 0.f;
    float s = pv;
#pragma unroll
    for (int off = 32; off > 0; off >>= 1) s += __shfl_xor(s, off);
    __syncthreads();
    if (lane == 0) red[hg][wig] = s;
    __syncthreads();
    s = red[hg][0] + red[hg][1] + red[hg][2] + red[hg][3];
    if (!(s > 1e-30f)) s = 1.f;
    att[h * 256 + tj] = pv / s;  // all 256 j written: masked tail becomes exact 0
    __syncthreads();
  }

  // attn @ V: threads < 512, one (h,d) each; att rows broadcast from LDS
  if (t < 512) {
    const int h = t >> 6, d = t & 63;
    const USHORT* vrow = v_t + (long)(h * 64 + d) * 512 + b * 256;
    const float* arow = &att[h * 256];
    float acc = 0.f;
    const int tl4 = (tl + 3) & ~3;
    for (int jj = 0; jj < tl4; jj += 4) {
      ushort4 vv = *(const ushort4*)(vrow + jj);
      acc += arow[jj + 0] * bf2f(vv.x) + arow[jj + 1] * bf2f(vv.y) +
             arow[jj + 2] * bf2f(vv.z) + arow[jj + 3] * bf2f(vv.w);
    }
    out_pre[(long)(b * 256 + i) * 512 + h * 64 + d] = f2bf(acc);
  }
}

extern "C" void kernel_launch(void* const* d_in, const int* in_sizes, int n_in,
                              void* d_out, int out_size, void* d_ws, size_t ws_size,
                              hipStream_t stream) {
  (void)in_sizes; (void)n_in; (void)out_size; (void)ws_size;

  char* w = (char*)d_ws;
  auto take = [&](size_t n) { char* r = w; w += (n + 255) & ~(size_t)255; return r; };

  int* flags   = (int*)take(16);
  int* c_seq   = (int*)take(16);
  int* c_lex   = (int*)take(16);
  int* c_pos_s = (int*)take(2048);
  int* c_pos_e = (int*)take(2048);
  const int ns[18] = {262144,262144,262144,262656,1048576,512,262144,512,262144,512,
                      262144,512,262144,512,262144,512,512,512};
  USHORT* canon[18];
  for (int i = 0; i < 18; i++) canon[i] = (USHORT*)take((size_t)ns[i] * 2);
  USHORT* WrT     = (USHORT*)take((size_t)262144 * 2);
  USHORT* q_n     = (USHORT*)take((size_t)262144 * 2);
  USHORT* k_n     = (USHORT*)take((size_t)262144 * 2);
  USHORT* v_t     = (USHORT*)take((size_t)262144 * 2);
  USHORT* wbuf    = (USHORT*)take((size_t)2097152 * 2);
  USHORT* Ptab    = (USHORT*)take((size_t)1050624 * 2);
  USHORT* T       = (USHORT*)take((size_t)12825 * 512 * 2);
  USHORT* vwr     = (USHORT*)take((size_t)4096 * 2);
  USHORT* out_pre = (USHORT*)take((size_t)262144 * 2);
  float* S   = (float*)take((size_t)1048576 * 4);   // S_AC only
  float* cbv = (float*)take((size_t)4096 * 4);
  float* uk  = (float*)take((size_t)4096 * 4);

  // 1) prep
  PrepArgs pa;
  for (int i = 0; i < 18; i++) { pa.fsrc[i] = d_in[i]; pa.fdst[i] = canon[i]; pa.fn[i] = ns[i]; }
  pa.wr_src = d_in[12]; pa.wrT = WrT;
  for (int i = 0; i < 4; i++) pa.isrc[i] = d_in[18 + i];
  pa.idst[0] = c_seq; pa.idst[1] = c_lex; pa.idst[2] = c_pos_s; pa.idst[3] = c_pos_e;
  prep_k<<<dim3(64, 20), 256, 0, stream>>>(pa, d_in[1], flags);

  // 2) g1: P tables (bf16, +bf in tbl0) + q/k (bf16) + v (bf16, transposed)
  GArgs gA = {};
  for (int z = 0; z < 4; z++)
    gA.d[z] = {canon[3], canon[4], (z == 0) ? canon[5] : nullptr, Ptab + (long)z * 513 * 512,
               513, 512, 512, 512, 2048, z * 512, 512, 1, 0, 0};
  gA.d[4] = {canon[1], canon[8],  canon[9],  q_n, 512, 512, 512, 512, 512, 0, 512, 1, 0, 0};
  gA.d[5] = {canon[0], canon[6],  canon[7],  k_n, 512, 512, 512, 512, 512, 0, 512, 1, 0, 0};
  gA.d[6] = {canon[2], canon[10], canon[11], v_t, 512, 512, 512, 512, 512, 0, 512, 1, 1, 0};
  gemm2_k<<<dim3(8, 9, 7), 256, 0, stream>>>(gA, flags);

  // 3) mid: T table + cbv + uk + vwr
  mid_k<<<512, 256, 0, stream>>>(Ptab, q_n, k_n, WrT, canon[16], canon[17], canon[13],
                                 T, cbv, uk, vwr);

  // 4) g2: wproj (q@WrT + vwr bias, bf16) + S_AC (q@k^T, f32 into S)
  GArgs gB = {};
  for (int z = 0; z < 16; z++) {
    const int b = z >> 3, h = z & 7;
    gB.d[z] = {q_n + b * 131072 + h * 64, WrT, vwr + h * 512, wbuf + (long)z * 131072,
               256, 512, 64, 512, 512, h * 64, 512, 1, 0, 0};
  }
  for (int z = 0; z < 16; z++) {
    const int b = z >> 3, h = z & 7;
    gB.d[16 + z] = {q_n + b * 131072 + h * 64, k_n + b * 131072 + h * 64, nullptr,
                    S + (long)z * 65536, 256, 256, 64, 512, 512, 0, 256, 0, 0, 0};
  }
  gemm2_k<<<dim3(8, 4, 32), 256, 0, stream>>>(gB, flags);

  // 5) fused score + softmax + attn@V -> out_pre (bf16)
  score6_k<<<dim3(256, 2), 1024, 0, stream>>>(
      T, cbv, uk, wbuf, S, v_t, c_seq, c_lex, c_pos_s, c_pos_e, out_pre);

  // 6) final: out = out_pre @ Wo.T + bo -> d_out (dtype per flag)
  GArgs gC = {};
  gC.d[0] = {out_pre, canon[14], canon[15], d_out, 512, 512, 512, 512, 512, 0, 512, 2, 0, 0};
  gemm2_k<<<dim3(8, 8, 1), 256, 0, stream>>>(gC, flags);
}